// Round 2
// baseline (72.079 us; speedup 1.0000x reference)
//
#include <hip/hip_runtime.h>

// Quanv2D surrogate:
// out[b, c*4+e, h, w] = 0.1 * precision * sin^2(0.5 * <patch(b,c,h,w), weight[c*4+e]>)
//                     = 0.05 * precision * (1 - cos(<patch, weight_row>))
// patch k-order: (h,w), (h,w+1), (h+1,w), (h+1,w+1)
// Shapes: x[64,4,224,224] f32, weight[16,4] f32, precision int, out[64,16,223,223] f32.
//
// R2: 4 output rows per block (5 x-rows loaded, interior register-reused:
// x fetch 2.0 -> 1.25 rows/output-row) + nontemporal output stores (pure
// stream, keep x resident in L2/LLC).

#define IW 224
#define IH 224
#define OW 223
#define OH 223
#define C_IN 4
#define E_EXT 4
#define R_ROWS 4

__global__ __launch_bounds__(256) void quanv2d_kernel(
    const float* __restrict__ x,      // [B,4,224,224]
    const float* __restrict__ wt,     // [16,4]
    const int*   __restrict__ prec,   // [1]
    float*       __restrict__ out)    // [B,16,223,223]
{
    const int w = threadIdx.x;                 // output col
    if (w >= OW) return;
    const int h0 = blockIdx.y * R_ROWS;        // first output row of this block
    const int bc = blockIdx.z;                 // b*4 + c
    const int b  = bc >> 2;
    const int c  = bc & 3;
    const int nr = min(R_ROWS, OH - h0);       // rows this block produces (4, or 3 in tail)

    const float scale = 0.05f * (float)(*prec);          // uniform -> SGPR

    // weight rows for this c: 16 floats, block-uniform -> s_load
    const float* wr = wt + (c * E_EXT) * 4;
    float wk[E_EXT][4];
#pragma unroll
    for (int e = 0; e < E_EXT; ++e)
#pragma unroll
        for (int k = 0; k < 4; ++k)
            wk[e][k] = wr[e * 4 + k];

    // load x rows h0 .. h0+nr (nr+1 rows), columns w and w+1
    const float* xp = x + (bc * IH + h0) * IW + w;
    float xa[R_ROWS + 1], xb[R_ROWS + 1];
#pragma unroll
    for (int r = 0; r <= R_ROWS; ++r) {
        if (r <= nr) {
            xa[r] = xp[r * IW];
            xb[r] = xp[r * IW + 1];
        }
    }

    float* op = out + ((b * (C_IN * E_EXT) + c * E_EXT) * OH + h0) * OW + w;

#pragma unroll
    for (int r = 0; r < R_ROWS; ++r) {
        if (r < nr) {
#pragma unroll
            for (int e = 0; e < E_EXT; ++e) {
                const float angle = xa[r]     * wk[e][0] + xb[r]     * wk[e][1]
                                  + xa[r + 1] * wk[e][2] + xb[r + 1] * wk[e][3];
                const float v = scale * (1.0f - __cosf(angle));
                __builtin_nontemporal_store(v, op + (e * OH + r) * OW);
            }
        }
    }
}

extern "C" void kernel_launch(void* const* d_in, const int* in_sizes, int n_in,
                              void* d_out, int out_size, void* d_ws, size_t ws_size,
                              hipStream_t stream)
{
    const float* x    = (const float*)d_in[0];
    const float* wt   = (const float*)d_in[1];
    const int*   prec = (const int*)d_in[2];
    float*       out  = (float*)d_out;

    const int B = 64;
    dim3 block(256, 1, 1);
    dim3 grid(1, (OH + R_ROWS - 1) / R_ROWS, B * C_IN);   // (1, 56, 256)
    quanv2d_kernel<<<grid, block, 0, stream>>>(x, wt, prec, out);
}

// Round 3
// 40.173 us; speedup vs baseline: 1.7942x; 1.7942x over previous
//
#include <hip/hip_runtime.h>

// Quanv2D surrogate:
// out[b, c*4+e, h, w] = 0.1 * precision * sin^2(0.5 * <patch(b,c,h,w), weight[c*4+e]>)
//                     = 0.05 * precision * (1 - cos(<patch, weight_row>))
// patch k-order: (h,w), (h,w+1), (h+1,w), (h+1,w+1)
// Shapes: x[64,4,224,224] f32, weight[16,4] f32, precision int, out[64,16,223,223] f32.
//
// R3: R1 structure (1 output row per block, 4 channels per thread, plain
// stores) + bijective XCD swizzle. 57088 blocks = 8 XCDs x 7136, and
// 7136 = 32 planes x 223 rows, so each XCD owns 32 whole (b,c) planes:
// x rows are read within one L2, and output lines merge fully in L2.

#define IW 224
#define IH 224
#define OW 223
#define OH 223
#define C_IN 4
#define E_EXT 4
#define NBLK (OH * C_IN * 64)      // 223 * 256 = 57088
#define PER_XCD (NBLK / 8)         // 7136 = 32 * 223

__global__ __launch_bounds__(256) void quanv2d_kernel(
    const float* __restrict__ x,      // [B,4,224,224]
    const float* __restrict__ wt,     // [16,4]
    const int*   __restrict__ prec,   // [1]
    float*       __restrict__ out)    // [B,16,223,223]
{
    const int w = threadIdx.x;                 // output col
    if (w >= OW) return;

    // XCD-aware bijective remap: each XCD gets a contiguous idx band.
    const int lb  = blockIdx.x;
    const int idx = (lb & 7) * PER_XCD + (lb >> 3);
    const int bc  = idx / OH;                  // b*4 + c  (plane id)
    const int h   = idx - bc * OH;             // output row
    const int b   = bc >> 2;
    const int c   = bc & 3;

    // patch loads (coalesced along w; +1 offsets are L1 hits)
    const float* xp = x + (bc * IH + h) * IW + w;
    const float p0 = xp[0];
    const float p1 = xp[1];
    const float p2 = xp[IW];
    const float p3 = xp[IW + 1];

    const float scale = 0.05f * (float)(*prec);            // uniform -> SGPR

    float* op = out + ((b * (C_IN * E_EXT) + c * E_EXT) * OH + h) * OW + w;
    const float* wr = wt + (c * E_EXT) * 4;                // uniform -> s_load

#pragma unroll
    for (int e = 0; e < E_EXT; ++e) {
        const float angle = p0 * wr[e * 4 + 0] + p1 * wr[e * 4 + 1]
                          + p2 * wr[e * 4 + 2] + p3 * wr[e * 4 + 3];
        op[e * (OH * OW)] = scale * (1.0f - __cosf(angle));
    }
}

extern "C" void kernel_launch(void* const* d_in, const int* in_sizes, int n_in,
                              void* d_out, int out_size, void* d_ws, size_t ws_size,
                              hipStream_t stream)
{
    const float* x    = (const float*)d_in[0];
    const float* wt   = (const float*)d_in[1];
    const int*   prec = (const int*)d_in[2];
    float*       out  = (float*)d_out;

    dim3 block(256, 1, 1);
    dim3 grid(NBLK, 1, 1);                     // 57088 blocks, XCD-swizzled
    quanv2d_kernel<<<grid, block, 0, stream>>>(x, wt, prec, out);
}